// Round 11
// baseline (431.175 us; speedup 1.0000x reference)
//
#include <hip/hip_runtime.h>
#include <stdint.h>

#define D_IN   256
#define D_OUT  64
#define KHEADS 4
#define ROWLEN 256       // K * D_OUT elements per node row in out
#define GBM    128       // GEMM rows per block
#define LDW    264       // lWt row stride in bf16 (528 B): ds_read_b128 2-way max (free)
#define WBT_B  (64 * LDW * 2)   // 33792 B: transposed bf16 W, identical layout to lWt
#define CAP    128       // edges-per-row bucket capacity (Poisson(16): P(>=128) ~ 1e-60)

typedef __attribute__((ext_vector_type(8))) short bf16x8;
typedef __attribute__((ext_vector_type(4))) float f32x4;

// HW packed fp32->bf16 (RNE), S0 -> low 16, S1 -> high 16. No builtin on gfx950.
__device__ __forceinline__ unsigned cvt_pk_bf16(float lo, float hi) {
  unsigned r;
  asm("v_cvt_pk_bf16_f32 %0, %1, %2" : "=v"(r) : "v"(lo), "v"(hi));
  return r;
}

__device__ __forceinline__ bf16x8 pack8(float4 a, float4 b) {
  union { unsigned u[4]; bf16x8 v; } r;
  r.u[0] = cvt_pk_bf16(a.x, a.y);
  r.u[1] = cvt_pk_bf16(a.z, a.w);
  r.u[2] = cvt_pk_bf16(b.x, b.y);
  r.u[3] = cvt_pk_bf16(b.z, b.w);
  return r.v;
}

// ---------------------------------------------------------------------------
// prep_w: one-time W[256,64] fp32 -> WbT bf16 transposed, padded to LDW,
// byte-identical to the lWt layout every gemm block stages. 16 blocks, ~2 us.
// ---------------------------------------------------------------------------
__global__ __launch_bounds__(256) void prep_w(const float* __restrict__ W,
                                              unsigned short* __restrict__ WbT) {
  int idx = blockIdx.x * 256 + threadIdx.x;   // 0..4095
  int n  = idx >> 6;                          // 0..63  (output col)
  int k0 = (idx & 63) << 2;                   // 0..252 (k quad)
  float w0 = W[(size_t)(k0 + 0) * D_OUT + n];
  float w1 = W[(size_t)(k0 + 1) * D_OUT + n];
  float w2 = W[(size_t)(k0 + 2) * D_OUT + n];
  float w3 = W[(size_t)(k0 + 3) * D_OUT + n];
  unsigned p0 = cvt_pk_bf16(w0, w1);
  unsigned p1 = cvt_pk_bf16(w2, w3);
  *(uint2*)&WbT[(size_t)n * LDW + k0] = make_uint2(p0, p1);
}

// ---------------------------------------------------------------------------
// place_kernel: STANDALONE bucketed edge placement (raw value; scale applied
// in gather). No LDS, tiny blocks, huge grid -> scatter/atomic latency hidden
// by TLP without poisoning the gemm's memory pipeline (R10 measured: inlining
// this into gemm made the gemm latency-bound at 16% HBM / 4% VALU).
// ---------------------------------------------------------------------------
__global__ __launch_bounds__(256) void place_kernel(const int* __restrict__ rows,
                                                    const int* __restrict__ cols,
                                                    const float* __restrict__ vals,
                                                    int* __restrict__ cnt,
                                                    uint2* __restrict__ ecv, int E) {
  int e = blockIdx.x * 256 + threadIdx.x;
  if (e < E) {
    int r = rows[e];
    int c = cols[e];
    float v = vals[e];
    int pos = atomicAdd(&cnt[r], 1);
    if (pos < CAP)
      ecv[((size_t)r << 7) + pos] = make_uint2((unsigned)c, __float_as_uint(v));
  }
}

// ---------------------------------------------------------------------------
// gemm_kernel: S[M,64] = X[M,256] @ W[256,64] via bf16 MFMA (fp32 acc).
// 3-SLOT SOFTWARE-PIPELINED A loads (2-step lookahead): p[3][4] float4 is
// indexed only by compile-time values under full unroll -> registers (rule
// #20). First 2 slots issued BEFORE lWt staging so they fly during the copy
// + barrier. Replaces the 8-deep serial load chain (R10: latency-bound).
// __launch_bounds__(256,4): cap VGPR <= 128 so LDS-capped 4 blocks/CU holds.
// Output head-major SqH[head][node][64] int8, per-node symmetric quant.
// C/D mapping (HW-verified): row = wave*32+rb*16+q*4+reg, col = cb*16+l16.
// ---------------------------------------------------------------------------
__global__ __launch_bounds__(256, 4) void gemm_kernel(
    const float* __restrict__ X, const unsigned short* __restrict__ WbT,
    signed char* __restrict__ SqH, float* __restrict__ scaleArr,
    int M, int Nnodes) {
  __shared__ __align__(16) unsigned short lWt[64 * LDW];   // 33792 B
  const int t    = threadIdx.x;
  const int g    = blockIdx.x;
  const int wave = t >> 6;
  const int lane = t & 63;
  const int q    = lane >> 4;
  const int l16  = lane & 15;
  const long row0 = (long)g * GBM;

  long r0 = row0 + wave * 32 + l16;       if (r0 > (long)M - 1) r0 = M - 1;
  long r1 = row0 + wave * 32 + 16 + l16;  if (r1 > (long)M - 1) r1 = M - 1;
  const float* __restrict__ x0 = X + r0 * D_IN + q * 8;
  const float* __restrict__ x1 = X + r1 * D_IN + q * 8;

  // Pipeline slots (all indices compile-time under full unroll -> registers).
  float4 p[3][4];
#pragma unroll
  for (int s = 0; s < 2; ++s) {          // prologue: 8 loads in flight
    p[s][0] = *(const float4*)(x0 + s * 32);
    p[s][1] = *(const float4*)(x0 + s * 32 + 4);
    p[s][2] = *(const float4*)(x1 + s * 32);
    p[s][3] = *(const float4*)(x1 + s * 32 + 4);
  }

  // Stage lWt (vectorized copy of precomputed WbT) while A loads fly.
  {
    const uint4* __restrict__ src = (const uint4*)WbT;
    uint4* dst = (uint4*)lWt;
#pragma unroll
    for (int r2 = 0; r2 < 9; ++r2) {
      int slot = t + r2 * 256;
      if (slot < WBT_B / 16) dst[slot] = src[slot];
    }
  }
  __syncthreads();

  f32x4 acc[2][4];
#pragma unroll
  for (int rb = 0; rb < 2; ++rb)
#pragma unroll
    for (int cb = 0; cb < 4; ++cb) acc[rb][cb] = (f32x4){0.f, 0.f, 0.f, 0.f};

#pragma unroll
  for (int s = 0; s < 8; ++s) {
    const int cs = s % 3;
    if (s + 2 < 8) {                     // issue 2-ahead
      const int ns = (s + 2) % 3;
      p[ns][0] = *(const float4*)(x0 + (s + 2) * 32);
      p[ns][1] = *(const float4*)(x0 + (s + 2) * 32 + 4);
      p[ns][2] = *(const float4*)(x1 + (s + 2) * 32);
      p[ns][3] = *(const float4*)(x1 + (s + 2) * 32 + 4);
    }
    bf16x8 a0 = pack8(p[cs][0], p[cs][1]);
    bf16x8 a1 = pack8(p[cs][2], p[cs][3]);
    const unsigned short* wb = &lWt[l16 * LDW + s * 32 + q * 8];
#pragma unroll
    for (int cb = 0; cb < 4; ++cb) {
      bf16x8 b = *(const bf16x8*)(wb + cb * 16 * LDW);
      acc[0][cb] = __builtin_amdgcn_mfma_f32_16x16x32_bf16(a0, b, acc[0][cb], 0, 0, 0);
      acc[1][cb] = __builtin_amdgcn_mfma_f32_16x16x32_bf16(a1, b, acc[1][cb], 0, 0, 0);
    }
  }

  // ---- Epilogue: per-node max -> scale -> int8 quantize (head-major) ----
  float nm0 = 0.f, nm1 = 0.f;
#pragma unroll
  for (int cb = 0; cb < 4; ++cb)
#pragma unroll
    for (int reg = 0; reg < 4; ++reg) {
      nm0 = fmaxf(nm0, fabsf(acc[0][cb][reg]));
      nm1 = fmaxf(nm1, fabsf(acc[1][cb][reg]));
    }
#pragma unroll
  for (int d = 1; d < 16; d <<= 1) {   // butterfly within 16-lane l16 group
    nm0 = fmaxf(nm0, __shfl_xor(nm0, d, 64));
    nm1 = fmaxf(nm1, __shfl_xor(nm1, d, 64));
  }
  const float inv0 = (nm0 > 0.f) ? 127.f / nm0 : 0.f;
  const float inv1 = (nm1 > 0.f) ? 127.f / nm1 : 0.f;
  const int node_base = g * 32 + wave * 8;
  if (l16 == 0) {
    int n0 = node_base + q;
    int n1 = node_base + 4 + q;
    if (n0 < Nnodes) scaleArr[n0] = nm0 / 127.f;
    if (n1 < Nnodes) scaleArr[n1] = nm1 / 127.f;
  }
#pragma unroll
  for (int rb = 0; rb < 2; ++rb) {
    const float inv = rb ? inv1 : inv0;
#pragma unroll
    for (int cb = 0; cb < 4; ++cb)
#pragma unroll
      for (int reg = 0; reg < 4; ++reg) {
        long r = row0 + wave * 32 + rb * 16 + q * 4 + reg;
        if (r < M) {
          int qi = (int)rintf(acc[rb][cb][reg] * inv);
          int node = (int)(r >> 2);
          int head = (int)(r & 3);
          SqH[((size_t)head * Nnodes + node) * 64 + cb * 16 + l16] = (signed char)qi;
        }
      }
  }
}

// ---------------------------------------------------------------------------
// Gather-accumulate + ReLU, HEAD-SPLIT for per-XCD L2 residency (unchanged
// from R10, which passed). EXEC-UNIFORM: mc/mv zero-masked at load, loop to
// ceil8(d0), unguarded __shfl (full exec, lane index <= 63).
// ---------------------------------------------------------------------------
__global__ __launch_bounds__(256) void gather_kernel(
    const signed char* __restrict__ SqH, const float* __restrict__ scaleArr,
    const int* __restrict__ cnt, const uint2* __restrict__ ecv,
    float* __restrict__ out, int n, int bph) {
  const int bid  = blockIdx.x;
  const int head = bid / bph;
  const int rb   = (bid - head * bph) * 4 + (threadIdx.x >> 6);
  if (rb >= n) return;
  const int lane = threadIdx.x & 63;
  const int e2   = lane >> 4;
  const int d16  = lane & 15;
  int deg = cnt[rb];
  if (deg > CAP) deg = CAP;
  const uint2* __restrict__ bucket = ecv + ((size_t)rb << 7);

  unsigned long long bl = *((const unsigned long long*)bucket + lane);
  const unsigned mc = (lane < deg) ? (unsigned)bl : 0u;
  const float    mv = (lane < deg)
      ? __uint_as_float((unsigned)(bl >> 32)) * scaleArr[mc] : 0.f;

  const int* __restrict__ Sh = (const int*)SqH + (size_t)head * (size_t)n * 16;

  float4 aA = make_float4(0.f, 0.f, 0.f, 0.f);
  float4 aB = aA;
  const int d0  = deg < 64 ? deg : 64;
  const int nd0 = (d0 + 7) & ~7;           // multiple of 8, <= 64
  for (int i = 0; i < nd0; i += 8) {       // 8 edges/iter, 2 loads in flight
    const int eA = i + e2;                 // <= 59
    const int eB = i + 4 + e2;             // <= 63
    const unsigned cA = __shfl(mc, eA);
    const unsigned cB = __shfl(mc, eB);
    const float    vA = __shfl(mv, eA);    // 0 for padding edges
    const float    vB = __shfl(mv, eB);
    const int wA = Sh[(size_t)cA * 16 + d16];
    const int wB = Sh[(size_t)cB * 16 + d16];
    aA.x += vA * (float)(wA << 24 >> 24); aA.y += vA * (float)(wA << 16 >> 24);
    aA.z += vA * (float)(wA <<  8 >> 24); aA.w += vA * (float)(wA >> 24);
    aB.x += vB * (float)(wB << 24 >> 24); aB.y += vB * (float)(wB << 16 >> 24);
    aB.z += vB * (float)(wB <<  8 >> 24); aB.w += vB * (float)(wB >> 24);
  }
  if (deg > 64) {  // Poisson(16): effectively never; correctness path only.
    unsigned long long bl1 = *((const unsigned long long*)bucket + 64 + lane);
    const unsigned mc1 = (64 + lane < deg) ? (unsigned)bl1 : 0u;
    const float    mv1 = (64 + lane < deg)
        ? __uint_as_float((unsigned)(bl1 >> 32)) * scaleArr[mc1] : 0.f;
    const int ndt = (deg + 3) & ~3;        // <= 128
    for (int i = 64; i < ndt; i += 4) {
      const int idx = i + e2 - 64;         // <= 63
      const unsigned cA = __shfl(mc1, idx);
      const float    vA = __shfl(mv1, idx);
      const int wA = Sh[(size_t)cA * 16 + d16];
      aA.x += vA * (float)(wA << 24 >> 24); aA.y += vA * (float)(wA << 16 >> 24);
      aA.z += vA * (float)(wA <<  8 >> 24); aA.w += vA * (float)(wA >> 24);
    }
  }
  float4 a;
  a.x = aA.x + aB.x; a.y = aA.y + aB.y; a.z = aA.z + aB.z; a.w = aA.w + aB.w;
  a.x += __shfl_xor(a.x, 16, 64); a.y += __shfl_xor(a.y, 16, 64);
  a.z += __shfl_xor(a.z, 16, 64); a.w += __shfl_xor(a.w, 16, 64);
  a.x += __shfl_xor(a.x, 32, 64); a.y += __shfl_xor(a.y, 32, 64);
  a.z += __shfl_xor(a.z, 32, 64); a.w += __shfl_xor(a.w, 32, 64);
  if (e2 == 0) {
    f32x4 res;
    res[0] = fmaxf(a.x, 0.f);
    res[1] = fmaxf(a.y, 0.f);
    res[2] = fmaxf(a.z, 0.f);
    res[3] = fmaxf(a.w, 0.f);
    __builtin_nontemporal_store(
        res, (f32x4*)&out[(size_t)rb * ROWLEN + head * 64 + (d16 << 2)]);
  }
}

// ---------------------------------------------------------------------------
extern "C" void kernel_launch(void* const* d_in, const int* in_sizes, int n_in,
                              void* d_out, int out_size, void* d_ws, size_t ws_size,
                              hipStream_t stream) {
  const float* x    = (const float*)d_in[0];
  const float* w    = (const float*)d_in[1];
  const int*   rows = (const int*)d_in[2];
  const int*   cols = (const int*)d_in[3];
  const float* vals = (const float*)d_in[4];
  float* out = (float*)d_out;

  const int E = in_sizes[2];
  const int N = in_sizes[0] / (KHEADS * D_IN);   // 50000 nodes
  const int M = N * KHEADS;                      // 200000 GEMM rows

  char* ws = (char*)d_ws;
  size_t o = 0;
  signed char* SqH = (signed char*)(ws + o); o += (size_t)M * D_OUT;  // 12.8 MB
  o = (o + 15) & ~(size_t)15;
  float* scaleArr = (float*)(ws + o); o += (size_t)N * sizeof(float); // 200 KB
  o = (o + 15) & ~(size_t)15;
  int* cnt = (int*)(ws + o); o += (size_t)N * sizeof(int);            // 200 KB
  o = (o + 63) & ~(size_t)63;
  unsigned short* WbT = (unsigned short*)(ws + o); o += WBT_B;        // 33 KB
  o = (o + 15) & ~(size_t)15;
  uint2* ecv = (uint2*)(ws + o);                                      // 51.2 MB

  hipMemsetAsync(cnt, 0, (size_t)N * sizeof(int), stream);

  const int G = (M + GBM - 1) / GBM;             // 1563
  const int P = (E + 255) / 256;                 // 3125
  prep_w<<<16, 256, 0, stream>>>(w, WbT);
  place_kernel<<<P, 256, 0, stream>>>(rows, cols, vals, cnt, ecv, E);
  gemm_kernel<<<G, 256, 0, stream>>>(x, WbT, SqH, scaleArr, M, N);
  const int bph = (N + 3) / 4;                   // blocks per head pass
  gather_kernel<<<bph * KHEADS, 256, 0, stream>>>(SqH, scaleArr, cnt, ecv,
                                                  out, N, bph);
}

// Round 17
// 390.092 us; speedup vs baseline: 1.1053x; 1.1053x over previous
//
#include <hip/hip_runtime.h>
#include <stdint.h>

#define D_IN   256
#define D_OUT  64
#define KHEADS 4
#define ROWLEN 256       // K * D_OUT elements per node row in out
#define GBM    128       // GEMM rows per block
#define CAP    128       // edges-per-row bucket capacity (Poisson(16): P(>=128) ~ 1e-60)

typedef __attribute__((ext_vector_type(8))) short bf16x8;
typedef __attribute__((ext_vector_type(4))) float f32x4;

// HW packed fp32->bf16 (RNE), S0 -> low 16, S1 -> high 16. No builtin on gfx950.
__device__ __forceinline__ unsigned cvt_pk_bf16(float lo, float hi) {
  unsigned r;
  asm("v_cvt_pk_bf16_f32 %0, %1, %2" : "=v"(r) : "v"(lo), "v"(hi));
  return r;
}

// pack8 takes true ext-vector f32x4 (HIP float4 is a class type and is
// rejected by __builtin_nontemporal_load -- R14 compile failure).
__device__ __forceinline__ bf16x8 pack8(f32x4 a, f32x4 b) {
  union { unsigned u[4]; bf16x8 v; } r;
  r.u[0] = cvt_pk_bf16(a[0], a[1]);
  r.u[1] = cvt_pk_bf16(a[2], a[3]);
  r.u[2] = cvt_pk_bf16(b[0], b[1]);
  r.u[3] = cvt_pk_bf16(b[2], b[3]);
  return r.v;
}

// ---------------------------------------------------------------------------
// prep_w: one-time W[256,64] fp32 -> WbT bf16 transposed, COMPACT [64][256]
// (exactly 32 KB: L1/L2-resident broadcast operand for every gemm block).
// ---------------------------------------------------------------------------
__global__ __launch_bounds__(256) void prep_w(const float* __restrict__ W,
                                              unsigned short* __restrict__ WbT) {
  int idx = blockIdx.x * 256 + threadIdx.x;   // 0..4095
  int n  = idx >> 6;                          // 0..63  (output col)
  int k0 = (idx & 63) << 2;                   // 0..252 (k quad)
  float w0 = W[(size_t)(k0 + 0) * D_OUT + n];
  float w1 = W[(size_t)(k0 + 1) * D_OUT + n];
  float w2 = W[(size_t)(k0 + 2) * D_OUT + n];
  float w3 = W[(size_t)(k0 + 3) * D_OUT + n];
  unsigned p0 = cvt_pk_bf16(w0, w1);
  unsigned p1 = cvt_pk_bf16(w2, w3);
  *(uint2*)&WbT[(size_t)n * D_IN + k0] = make_uint2(p0, p1);
}

// ---------------------------------------------------------------------------
// GEMM body, NO LDS: B fragments read directly from global WbT (32 KB,
// shared by all blocks -> L1/L2 resident). Removes the staging barrier whose
// compiler-emitted s_waitcnt vmcnt(0) drained the A prefetch pipeline
// (R10: 16% HBM, 1.8% MFMA, latency-bound). A loads NONTEMPORAL (streaming).
// Occupancy now VGPR-capped, not LDS-capped.
// Output NODE-MAJOR Sq[r][64] (r = node*4+head), per-node symmetric quant.
// C/D mapping (HW-verified): row = wave*32+rb*16+q*4+reg, col = cb*16+l16.
// ---------------------------------------------------------------------------
__device__ __forceinline__ void gemm_body(const float* __restrict__ X,
                                          const unsigned short* __restrict__ WbT,
                                          signed char* __restrict__ Sq,
                                          float* __restrict__ scaleArr,
                                          int M, int Nnodes, int g) {
  const int t    = threadIdx.x;
  const int wave = t >> 6;
  const int lane = t & 63;
  const int q    = lane >> 4;
  const int l16  = lane & 15;
  const long row0 = (long)g * GBM;

  long r0 = row0 + wave * 32 + l16;       if (r0 > (long)M - 1) r0 = M - 1;
  long r1 = row0 + wave * 32 + 16 + l16;  if (r1 > (long)M - 1) r1 = M - 1;
  const float* __restrict__ x0 = X + r0 * D_IN + q * 8;
  const float* __restrict__ x1 = X + r1 * D_IN + q * 8;
  const unsigned short* __restrict__ wrow = WbT + (size_t)l16 * D_IN + q * 8;

  f32x4 acc[2][4];
#pragma unroll
  for (int rb = 0; rb < 2; ++rb)
#pragma unroll
    for (int cb = 0; cb < 4; ++cb) acc[rb][cb] = (f32x4){0.f, 0.f, 0.f, 0.f};

  // K-loop: 8 steps of K=32; 1-step register prefetch. A = nontemporal.
  f32x4 c00 = __builtin_nontemporal_load((const f32x4*)(x0));
  f32x4 c01 = __builtin_nontemporal_load((const f32x4*)(x0 + 4));
  f32x4 c10 = __builtin_nontemporal_load((const f32x4*)(x1));
  f32x4 c11 = __builtin_nontemporal_load((const f32x4*)(x1 + 4));
#pragma unroll
  for (int s = 0; s < 8; ++s) {
    f32x4 n00, n01, n10, n11;
    if (s < 7) {
      const float* p0 = x0 + (s + 1) * 32;
      const float* p1 = x1 + (s + 1) * 32;
      n00 = __builtin_nontemporal_load((const f32x4*)(p0));
      n01 = __builtin_nontemporal_load((const f32x4*)(p0 + 4));
      n10 = __builtin_nontemporal_load((const f32x4*)(p1));
      n11 = __builtin_nontemporal_load((const f32x4*)(p1 + 4));
    }
    bf16x8 a0 = pack8(c00, c01);
    bf16x8 a1 = pack8(c10, c11);
#pragma unroll
    for (int cb = 0; cb < 4; ++cb) {
      bf16x8 b = *(const bf16x8*)(wrow + (size_t)cb * 16 * D_IN + s * 32);
      acc[0][cb] = __builtin_amdgcn_mfma_f32_16x16x32_bf16(a0, b, acc[0][cb], 0, 0, 0);
      acc[1][cb] = __builtin_amdgcn_mfma_f32_16x16x32_bf16(a1, b, acc[1][cb], 0, 0, 0);
    }
    if (s < 7) { c00 = n00; c01 = n01; c10 = n10; c11 = n11; }
  }

  // ---- Epilogue: per-node max -> scale -> int8 quantize (node-major) ----
  float nm0 = 0.f, nm1 = 0.f;
#pragma unroll
  for (int cb = 0; cb < 4; ++cb)
#pragma unroll
    for (int reg = 0; reg < 4; ++reg) {
      nm0 = fmaxf(nm0, fabsf(acc[0][cb][reg]));
      nm1 = fmaxf(nm1, fabsf(acc[1][cb][reg]));
    }
#pragma unroll
  for (int d = 1; d < 16; d <<= 1) {   // butterfly within 16-lane l16 group
    nm0 = fmaxf(nm0, __shfl_xor(nm0, d, 64));
    nm1 = fmaxf(nm1, __shfl_xor(nm1, d, 64));
  }
  const float inv0 = (nm0 > 0.f) ? 127.f / nm0 : 0.f;
  const float inv1 = (nm1 > 0.f) ? 127.f / nm1 : 0.f;
  const int node_base = g * 32 + wave * 8;
  if (l16 == 0) {
    int n0 = node_base + q;
    int n1 = node_base + 4 + q;
    if (n0 < Nnodes) scaleArr[n0] = nm0 / 127.f;
    if (n1 < Nnodes) scaleArr[n1] = nm1 / 127.f;
  }
#pragma unroll
  for (int rb = 0; rb < 2; ++rb) {
    const float inv = rb ? inv1 : inv0;
#pragma unroll
    for (int cb = 0; cb < 4; ++cb)
#pragma unroll
      for (int reg = 0; reg < 4; ++reg) {
        long r = row0 + wave * 32 + rb * 16 + q * 4 + reg;
        if (r < M) {
          int qi = (int)rintf(acc[rb][cb][reg] * inv);
          Sq[r * D_OUT + cb * 16 + l16] = (signed char)qi;
        }
      }
  }
}

// ---------------------------------------------------------------------------
// Place body: bucketed edge placement, RAW value (scale applied in gather).
// ---------------------------------------------------------------------------
__device__ __forceinline__ void place_body(const int* __restrict__ rows,
                                           const int* __restrict__ cols,
                                           const float* __restrict__ vals,
                                           int* __restrict__ cnt,
                                           uint2* __restrict__ ecv, int E, int pb) {
  int e = pb * 256 + threadIdx.x;
  if (e < E) {
    int r = rows[e];
    int c = cols[e];
    float v = vals[e];
    int pos = atomicAdd(&cnt[r], 1);
    if (pos < CAP)
      ecv[((size_t)r << 7) + pos] = make_uint2((unsigned)c, __float_as_uint(v));
  }
}

// ---------------------------------------------------------------------------
// Fused phase 1 (R4-proven 1:2 role split): 1 gemm block : 2 place blocks.
// Grid = 3*G; requires P <= 2*G (P=3125, 2G=3126). No LDS anywhere now.
// ---------------------------------------------------------------------------
__global__ __launch_bounds__(256) void fused_phase1(
    const float* __restrict__ X, const unsigned short* __restrict__ WbT,
    signed char* __restrict__ Sq, float* __restrict__ scaleArr,
    const int* __restrict__ rows, const int* __restrict__ cols,
    const float* __restrict__ vals, int* __restrict__ cnt,
    uint2* __restrict__ ecv, int M, int Nnodes, int E, int G, int P) {
  const int bid = blockIdx.x;
  const int g = bid / 3, r3 = bid - 3 * g;
  if (r3 == 0) {
    if (g < G) gemm_body(X, WbT, Sq, scaleArr, M, Nnodes, g);
  } else {
    int pb = 2 * g + r3 - 1;
    if (pb < P) place_body(rows, cols, vals, cnt, ecv, E, pb);
  }
}

// ---------------------------------------------------------------------------
// Gather-accumulate + ReLU (R4-proven node-major structure). One wave per
// node row; lane owns one dword (4 int8) of the 256 B node support row.
// Whole bucket -> registers in ONE coalesced nt load (lane i = entry i),
// scale folded per-lane once. EXEC-UNIFORM loop to ceil8(d0) with unguarded
// __shfl (uniform lane indices <= 63; padding edges contribute v=0).
// 8-wide body: 8 gathers in flight.
// ---------------------------------------------------------------------------
__global__ __launch_bounds__(256) void gather_kernel(
    const int* __restrict__ Sqi, const float* __restrict__ scaleArr,
    const int* __restrict__ cnt, const uint2* __restrict__ ecv,
    float* __restrict__ out, int n) {
  const int lane = threadIdx.x & 63;
  const int r = blockIdx.x * 4 + (threadIdx.x >> 6);
  if (r >= n) return;
  int deg = cnt[r];
  if (deg > CAP) deg = CAP;
  const uint2* __restrict__ bucket = ecv + ((size_t)r << 7);

  // One coalesced nt load of entries 0..63; zero-mask poisoned tail.
  unsigned long long bl =
      __builtin_nontemporal_load((const unsigned long long*)bucket + lane);
  const unsigned mc = (lane < deg) ? (unsigned)bl : 0u;
  const float    mv = (lane < deg)
      ? __uint_as_float((unsigned)(bl >> 32)) * scaleArr[mc] : 0.f;

  float4 a0 = make_float4(0.f, 0.f, 0.f, 0.f);
  float4 a1 = a0, a2 = a0, a3 = a0;
  const int d0  = deg < 64 ? deg : 64;
  const int nd0 = (d0 + 7) & ~7;           // multiple of 8, <= 64
  for (int i = 0; i < nd0; i += 8) {
    unsigned cc[8]; float vv[8]; int ww[8];
#pragma unroll
    for (int u = 0; u < 8; ++u) {
      cc[u] = __shfl(mc, i + u);           // uniform index <= 63, full exec
      vv[u] = __shfl(mv, i + u);           // 0 for padding edges
    }
#pragma unroll
    for (int u = 0; u < 8; ++u) ww[u] = Sqi[(size_t)cc[u] * 64 + lane];
#pragma unroll
    for (int u = 0; u < 8; ++u) {
      float4& a = ((u & 3) == 0) ? a0 : (((u & 3) == 1) ? a1 : (((u & 3) == 2) ? a2 : a3));
      const float v = vv[u];
      const int   w = ww[u];
      a.x += v * (float)(w << 24 >> 24);
      a.y += v * (float)(w << 16 >> 24);
      a.z += v * (float)(w <<  8 >> 24);
      a.w += v * (float)(w >> 24);
    }
  }
  if (deg > 64) {  // Poisson(16): effectively never; correctness path only.
    unsigned long long bl1 = *((const unsigned long long*)bucket + 64 + lane);
    const unsigned mc1 = (64 + lane < deg) ? (unsigned)bl1 : 0u;
    const float    mv1 = (64 + lane < deg)
        ? __uint_as_float((unsigned)(bl1 >> 32)) * scaleArr[mc1] : 0.f;
    const int ndt = ((deg - 64) + 7) & ~7; // multiple of 8, <= 64
    for (int i = 0; i < ndt; ++i) {
      const unsigned c = __shfl(mc1, i);
      const float    v = __shfl(mv1, i);
      const int w = Sqi[(size_t)c * 64 + lane];
      a0.x += v * (float)(w << 24 >> 24); a0.y += v * (float)(w << 16 >> 24);
      a0.z += v * (float)(w <<  8 >> 24); a0.w += v * (float)(w >> 24);
    }
  }
  f32x4 res;
  res[0] = fmaxf(a0.x + a1.x + a2.x + a3.x, 0.f);
  res[1] = fmaxf(a0.y + a1.y + a2.y + a3.y, 0.f);
  res[2] = fmaxf(a0.z + a1.z + a2.z + a3.z, 0.f);
  res[3] = fmaxf(a0.w + a1.w + a2.w + a3.w, 0.f);
  __builtin_nontemporal_store(res, (f32x4*)&out[(size_t)r * ROWLEN + (lane << 2)]);
}

// ---------------------------------------------------------------------------
extern "C" void kernel_launch(void* const* d_in, const int* in_sizes, int n_in,
                              void* d_out, int out_size, void* d_ws, size_t ws_size,
                              hipStream_t stream) {
  const float* x    = (const float*)d_in[0];
  const float* w    = (const float*)d_in[1];
  const int*   rows = (const int*)d_in[2];
  const int*   cols = (const int*)d_in[3];
  const float* vals = (const float*)d_in[4];
  float* out = (float*)d_out;

  const int E = in_sizes[2];
  const int N = in_sizes[0] / (KHEADS * D_IN);   // 50000 nodes
  const int M = N * KHEADS;                      // 200000 GEMM rows

  char* ws = (char*)d_ws;
  size_t o = 0;
  signed char* Sq = (signed char*)(ws + o); o += (size_t)M * D_OUT;   // 12.8 MB
  o = (o + 15) & ~(size_t)15;
  float* scaleArr = (float*)(ws + o); o += (size_t)N * sizeof(float); // 200 KB
  o = (o + 15) & ~(size_t)15;
  int* cnt = (int*)(ws + o); o += (size_t)N * sizeof(int);            // 200 KB
  o = (o + 63) & ~(size_t)63;
  unsigned short* WbT = (unsigned short*)(ws + o);
  o += (size_t)D_OUT * D_IN * sizeof(unsigned short);                 // 32 KB
  o = (o + 15) & ~(size_t)15;
  uint2* ecv = (uint2*)(ws + o);                                      // 51.2 MB

  (void)hipMemsetAsync(cnt, 0, (size_t)N * sizeof(int), stream);

  const int G = (M + GBM - 1) / GBM;             // 1563
  const int P = (E + 255) / 256;                 // 3125
  prep_w<<<16, 256, 0, stream>>>(w, WbT);
  fused_phase1<<<3 * G, 256, 0, stream>>>(x, WbT, Sq, scaleArr, rows, cols,
                                          vals, cnt, ecv, M, N, E, G, P);
  gather_kernel<<<(N + 3) / 4, 256, 0, stream>>>((const int*)Sq, scaleArr,
                                                 cnt, ecv, out, N);
}

// Round 19
// 389.420 us; speedup vs baseline: 1.1072x; 1.0017x over previous
//
#include <hip/hip_runtime.h>
#include <stdint.h>

#define D_IN   256
#define D_OUT  64
#define KHEADS 4
#define ROWLEN 256       // K * D_OUT elements per node row in out
#define GBM    256       // GEMM rows per block (512 thr / 8 waves, 32 rows/wave)
#define LDW    264       // lWt row stride in bf16 (528 B): ds_read_b128 2-way max (free)
#define WBT_B  (64 * LDW * 2)   // 33792 B: transposed bf16 W, identical layout to lWt
#define CAP    128       // edges-per-row bucket capacity (Poisson(16): P(>=128) ~ 1e-60)

typedef __attribute__((ext_vector_type(8))) short bf16x8;
typedef __attribute__((ext_vector_type(4))) float f32x4;

// HW packed fp32->bf16 (RNE), S0 -> low 16, S1 -> high 16. No builtin on gfx950.
__device__ __forceinline__ unsigned cvt_pk_bf16(float lo, float hi) {
  unsigned r;
  asm("v_cvt_pk_bf16_f32 %0, %1, %2" : "=v"(r) : "v"(lo), "v"(hi));
  return r;
}

__device__ __forceinline__ bf16x8 pack8(float4 a, float4 b) {
  union { unsigned u[4]; bf16x8 v; } r;
  r.u[0] = cvt_pk_bf16(a.x, a.y);
  r.u[1] = cvt_pk_bf16(a.z, a.w);
  r.u[2] = cvt_pk_bf16(b.x, b.y);
  r.u[3] = cvt_pk_bf16(b.z, b.w);
  return r.v;
}

// ---------------------------------------------------------------------------
// prep_w: one-time W[256,64] fp32 -> WbT bf16 transposed, padded to LDW,
// byte-identical to the lWt layout every gemm block stages. 16 blocks, ~2 us.
// ---------------------------------------------------------------------------
__global__ __launch_bounds__(256) void prep_w(const float* __restrict__ W,
                                              unsigned short* __restrict__ WbT) {
  int idx = blockIdx.x * 256 + threadIdx.x;   // 0..4095
  int n  = idx >> 6;                          // 0..63  (output col)
  int k0 = (idx & 63) << 2;                   // 0..252 (k quad)
  float w0 = W[(size_t)(k0 + 0) * D_OUT + n];
  float w1 = W[(size_t)(k0 + 1) * D_OUT + n];
  float w2 = W[(size_t)(k0 + 2) * D_OUT + n];
  float w3 = W[(size_t)(k0 + 3) * D_OUT + n];
  unsigned p0 = cvt_pk_bf16(w0, w1);
  unsigned p1 = cvt_pk_bf16(w2, w3);
  *(uint2*)&WbT[(size_t)n * LDW + k0] = make_uint2(p0, p1);
}

// ---------------------------------------------------------------------------
// GEMM body (R4-proven per-wave structure, now 8 waves/block @ GBM=256):
// LDS-staged WbT (vectorized copy, one barrier), per-wave 32 rows, acc[2][4],
// 1-step register A prefetch, plain float4 A loads.
// WHY 512 threads: 33.8 KB LDS capped R4 at 4 blk x 4 waves = 16 waves/CU
// (R10 measured Occ 35%, latency-bound). Same LDS at 8 waves/blk -> 4 blk x
// 8 waves = 32 waves/CU; staging+barrier amortized over 2x rows.
// __launch_bounds__(512,8) holds VGPR <= 64 (R10 measured 52 for this body).
// Output NODE-MAJOR Sq[r][64], per-node symmetric int8 quant.
// C/D mapping (HW-verified): row = wave*32+rb*16+q*4+reg, col = cb*16+l16.
// ---------------------------------------------------------------------------
__device__ __forceinline__ void gemm_body(const float* __restrict__ X,
                                          const unsigned short* __restrict__ WbT,
                                          signed char* __restrict__ Sq,
                                          float* __restrict__ scaleArr,
                                          int M, int Nnodes, int g,
                                          unsigned short* lWt) {
  const int t    = threadIdx.x;
  const int wave = t >> 6;            // 0..7
  const int lane = t & 63;
  const int q    = lane >> 4;
  const int l16  = lane & 15;
  const long row0 = (long)g * GBM;

  // Stage lWt: vectorized copy of precomputed WbT. 2112 uint4 slots,
  // 512 threads -> 5 guarded rounds.
  {
    const uint4* __restrict__ src = (const uint4*)WbT;
    uint4* dst = (uint4*)lWt;
#pragma unroll
    for (int r2 = 0; r2 < 5; ++r2) {
      int slot = t + r2 * 512;
      if (slot < WBT_B / 16) dst[slot] = src[slot];
    }
  }
  __syncthreads();

  long r0 = row0 + wave * 32 + l16;       if (r0 > (long)M - 1) r0 = M - 1;
  long r1 = row0 + wave * 32 + 16 + l16;  if (r1 > (long)M - 1) r1 = M - 1;
  const float* __restrict__ x0 = X + r0 * D_IN + q * 8;
  const float* __restrict__ x1 = X + r1 * D_IN + q * 8;

  f32x4 acc[2][4];
#pragma unroll
  for (int rb = 0; rb < 2; ++rb)
#pragma unroll
    for (int cb = 0; cb < 4; ++cb) acc[rb][cb] = (f32x4){0.f, 0.f, 0.f, 0.f};

  // K-loop: 8 steps of K=32; 1-step register prefetch (R4-proven).
  float4 c00 = *(const float4*)(x0);
  float4 c01 = *(const float4*)(x0 + 4);
  float4 c10 = *(const float4*)(x1);
  float4 c11 = *(const float4*)(x1 + 4);
#pragma unroll
  for (int s = 0; s < 8; ++s) {
    float4 n00, n01, n10, n11;
    if (s < 7) {
      const float* p0 = x0 + (s + 1) * 32;
      const float* p1 = x1 + (s + 1) * 32;
      n00 = *(const float4*)(p0); n01 = *(const float4*)(p0 + 4);
      n10 = *(const float4*)(p1); n11 = *(const float4*)(p1 + 4);
    }
    bf16x8 a0 = pack8(c00, c01);
    bf16x8 a1 = pack8(c10, c11);
    const unsigned short* wb = &lWt[l16 * LDW + s * 32 + q * 8];
#pragma unroll
    for (int cb = 0; cb < 4; ++cb) {
      bf16x8 b = *(const bf16x8*)(wb + cb * 16 * LDW);
      acc[0][cb] = __builtin_amdgcn_mfma_f32_16x16x32_bf16(a0, b, acc[0][cb], 0, 0, 0);
      acc[1][cb] = __builtin_amdgcn_mfma_f32_16x16x32_bf16(a1, b, acc[1][cb], 0, 0, 0);
    }
    if (s < 7) { c00 = n00; c01 = n01; c10 = n10; c11 = n11; }
  }

  // ---- Epilogue: per-node max -> scale -> int8 quantize (node-major) ----
  float nm0 = 0.f, nm1 = 0.f;
#pragma unroll
  for (int cb = 0; cb < 4; ++cb)
#pragma unroll
    for (int reg = 0; reg < 4; ++reg) {
      nm0 = fmaxf(nm0, fabsf(acc[0][cb][reg]));
      nm1 = fmaxf(nm1, fabsf(acc[1][cb][reg]));
    }
#pragma unroll
  for (int d = 1; d < 16; d <<= 1) {   // butterfly within 16-lane l16 group
    nm0 = fmaxf(nm0, __shfl_xor(nm0, d, 64));
    nm1 = fmaxf(nm1, __shfl_xor(nm1, d, 64));
  }
  const float inv0 = (nm0 > 0.f) ? 127.f / nm0 : 0.f;
  const float inv1 = (nm1 > 0.f) ? 127.f / nm1 : 0.f;
  const int node_base = g * 64 + wave * 8;   // 64 nodes/block, 8/wave
  if (l16 == 0) {
    int n0 = node_base + q;       // rb=0
    int n1 = node_base + 4 + q;   // rb=1
    if (n0 < Nnodes) scaleArr[n0] = nm0 / 127.f;
    if (n1 < Nnodes) scaleArr[n1] = nm1 / 127.f;
  }
#pragma unroll
  for (int rb = 0; rb < 2; ++rb) {
    const float inv = rb ? inv1 : inv0;
#pragma unroll
    for (int cb = 0; cb < 4; ++cb)
#pragma unroll
      for (int reg = 0; reg < 4; ++reg) {
        long r = row0 + wave * 32 + rb * 16 + q * 4 + reg;
        if (r < M) {
          int qi = (int)rintf(acc[rb][cb][reg] * inv);
          Sq[r * D_OUT + cb * 16 + l16] = (signed char)qi;
        }
      }
  }
}

// ---------------------------------------------------------------------------
// Place body: bucketed edge placement, RAW value (scale applied in gather).
// 512 edges per place block (one per thread).
// ---------------------------------------------------------------------------
__device__ __forceinline__ void place_body(const int* __restrict__ rows,
                                           const int* __restrict__ cols,
                                           const float* __restrict__ vals,
                                           int* __restrict__ cnt,
                                           uint2* __restrict__ ecv, int E, int pb) {
  int e = pb * 512 + threadIdx.x;
  if (e < E) {
    int r = rows[e];
    int c = cols[e];
    float v = vals[e];
    int pos = atomicAdd(&cnt[r], 1);
    if (pos < CAP)
      ecv[((size_t)r << 7) + pos] = make_uint2((unsigned)c, __float_as_uint(v));
  }
}

// ---------------------------------------------------------------------------
// Fused phase 1: 1 gemm block : 4 place blocks (G=782, P=1563 <= 4G=3128).
// Same role-interleave principle as R4's measured-best 1:2 config.
// ---------------------------------------------------------------------------
__global__ __launch_bounds__(512, 8) void fused_phase1(
    const float* __restrict__ X, const unsigned short* __restrict__ WbT,
    signed char* __restrict__ Sq, float* __restrict__ scaleArr,
    const int* __restrict__ rows, const int* __restrict__ cols,
    const float* __restrict__ vals, int* __restrict__ cnt,
    uint2* __restrict__ ecv, int M, int Nnodes, int E, int G, int P) {
  __shared__ __align__(16) unsigned short lWt[64 * LDW];   // 33792 B
  const int bid = blockIdx.x;
  const int g = bid / 5, r5 = bid - 5 * g;
  if (r5 == 0) {
    if (g < G) gemm_body(X, WbT, Sq, scaleArr, M, Nnodes, g, lWt);
  } else {
    int pb = 4 * g + r5 - 1;
    if (pb < P) place_body(rows, cols, vals, cnt, ecv, E, pb);
  }
}

// ---------------------------------------------------------------------------
// Gather-accumulate + ReLU (R17-proven, passed twice). One wave per node row;
// lane owns one dword (4 int8) of the 256 B node support row. Whole bucket ->
// registers in ONE coalesced nt load; scale folded per-lane once. EXEC-UNIFORM
// loop to ceil8(d0) with unguarded __shfl. 8-wide body: 8 gathers in flight.
// ---------------------------------------------------------------------------
__global__ __launch_bounds__(256) void gather_kernel(
    const int* __restrict__ Sqi, const float* __restrict__ scaleArr,
    const int* __restrict__ cnt, const uint2* __restrict__ ecv,
    float* __restrict__ out, int n) {
  const int lane = threadIdx.x & 63;
  const int r = blockIdx.x * 4 + (threadIdx.x >> 6);
  if (r >= n) return;
  int deg = cnt[r];
  if (deg > CAP) deg = CAP;
  const uint2* __restrict__ bucket = ecv + ((size_t)r << 7);

  // One coalesced nt load of entries 0..63; zero-mask poisoned tail.
  unsigned long long bl =
      __builtin_nontemporal_load((const unsigned long long*)bucket + lane);
  const unsigned mc = (lane < deg) ? (unsigned)bl : 0u;
  const float    mv = (lane < deg)
      ? __uint_as_float((unsigned)(bl >> 32)) * scaleArr[mc] : 0.f;

  float4 a0 = make_float4(0.f, 0.f, 0.f, 0.f);
  float4 a1 = a0, a2 = a0, a3 = a0;
  const int d0  = deg < 64 ? deg : 64;
  const int nd0 = (d0 + 7) & ~7;           // multiple of 8, <= 64
  for (int i = 0; i < nd0; i += 8) {
    unsigned cc[8]; float vv[8]; int ww[8];
#pragma unroll
    for (int u = 0; u < 8; ++u) {
      cc[u] = __shfl(mc, i + u);           // uniform index <= 63, full exec
      vv[u] = __shfl(mv, i + u);           // 0 for padding edges
    }
#pragma unroll
    for (int u = 0; u < 8; ++u) ww[u] = Sqi[(size_t)cc[u] * 64 + lane];
#pragma unroll
    for (int u = 0; u < 8; ++u) {
      float4& a = ((u & 3) == 0) ? a0 : (((u & 3) == 1) ? a1 : (((u & 3) == 2) ? a2 : a3));
      const float v = vv[u];
      const int   w = ww[u];
      a.x += v * (float)(w << 24 >> 24);
      a.y += v * (float)(w << 16 >> 24);
      a.z += v * (float)(w <<  8 >> 24);
      a.w += v * (float)(w >> 24);
    }
  }
  if (deg > 64) {  // Poisson(16): effectively never; correctness path only.
    unsigned long long bl1 = *((const unsigned long long*)bucket + 64 + lane);
    const unsigned mc1 = (64 + lane < deg) ? (unsigned)bl1 : 0u;
    const float    mv1 = (64 + lane < deg)
        ? __uint_as_float((unsigned)(bl1 >> 32)) * scaleArr[mc1] : 0.f;
    const int ndt = ((deg - 64) + 7) & ~7; // multiple of 8, <= 64
    for (int i = 0; i < ndt; ++i) {
      const unsigned c = __shfl(mc1, i);
      const float    v = __shfl(mv1, i);
      const int w = Sqi[(size_t)c * 64 + lane];
      a0.x += v * (float)(w << 24 >> 24); a0.y += v * (float)(w << 16 >> 24);
      a0.z += v * (float)(w <<  8 >> 24); a0.w += v * (float)(w >> 24);
    }
  }
  f32x4 res;
  res[0] = fmaxf(a0.x + a1.x + a2.x + a3.x, 0.f);
  res[1] = fmaxf(a0.y + a1.y + a2.y + a3.y, 0.f);
  res[2] = fmaxf(a0.z + a1.z + a2.z + a3.z, 0.f);
  res[3] = fmaxf(a0.w + a1.w + a2.w + a3.w, 0.f);
  __builtin_nontemporal_store(res, (f32x4*)&out[(size_t)r * ROWLEN + (lane << 2)]);
}

// ---------------------------------------------------------------------------
extern "C" void kernel_launch(void* const* d_in, const int* in_sizes, int n_in,
                              void* d_out, int out_size, void* d_ws, size_t ws_size,
                              hipStream_t stream) {
  const float* x    = (const float*)d_in[0];
  const float* w    = (const float*)d_in[1];
  const int*   rows = (const int*)d_in[2];
  const int*   cols = (const int*)d_in[3];
  const float* vals = (const float*)d_in[4];
  float* out = (float*)d_out;

  const int E = in_sizes[2];
  const int N = in_sizes[0] / (KHEADS * D_IN);   // 50000 nodes
  const int M = N * KHEADS;                      // 200000 GEMM rows

  char* ws = (char*)d_ws;
  size_t o = 0;
  signed char* Sq = (signed char*)(ws + o); o += (size_t)M * D_OUT;   // 12.8 MB
  o = (o + 15) & ~(size_t)15;
  float* scaleArr = (float*)(ws + o); o += (size_t)N * sizeof(float); // 200 KB
  o = (o + 15) & ~(size_t)15;
  int* cnt = (int*)(ws + o); o += (size_t)N * sizeof(int);            // 200 KB
  o = (o + 63) & ~(size_t)63;
  unsigned short* WbT = (unsigned short*)(ws + o); o += WBT_B;        // 33 KB
  o = (o + 15) & ~(size_t)15;
  uint2* ecv = (uint2*)(ws + o);                                      // 51.2 MB

  (void)hipMemsetAsync(cnt, 0, (size_t)N * sizeof(int), stream);

  const int G = (M + GBM - 1) / GBM;             // 782
  const int P = (E + 511) / 512;                 // 1563
  prep_w<<<16, 256, 0, stream>>>(w, WbT);
  fused_phase1<<<5 * G, 512, 0, stream>>>(x, WbT, Sq, scaleArr, rows, cols,
                                          vals, cnt, ecv, M, N, E, G, P);
  gather_kernel<<<(N + 3) / 4, 256, 0, stream>>>((const int*)Sq, scaleArr,
                                                 cnt, ecv, out, N);
}